// Round 2
// baseline (1257.909 us; speedup 1.0000x reference)
//
#include <hip/hip_runtime.h>
#include <math.h>

// VQ-VAE quantizer. Outputs in d_out (float32, flat, concat):
//   [0]                       loss
//   [1 .. 16777216]           quantized_st, NCHW [16,64,128,128]
//   [16777217]                perplexity
//   [16777218 .. +134217728)  encodings one-hot [262144, 512]
//
// ws layout (floats): [0..511] hist(int, atomics, zeroed via memset)
//                     [512..1023] b_k = ||e_k||^2 (numpy-pairwise exact)
//                     [1024..1535] per-block loss partials
//
// Numerics: argmin must match np fp32 reference exactly -> numpy pairwise
// sums (8-accumulator) for ||x||^2 and ||e||^2, sequential fp32 FMA chain
// for the dot (matches BLAS k-order; verified absmax 0.0 in R1),
// d = fma(-2,dot,fl(a+b)), strict < ascending-k scan.
//
// R2: embedding is wave-uniform -> scalar loads (SGPR operand FMA), no LDS
// in the inner loop; one-hot zeros paced into the k-loop so the 537 MB
// write stream overlaps compute; the single 1.0/row stored after
// __syncthreads (barrier's vmcnt(0) drain orders zero-stores first).

#define NTOK    262144
#define KCODES  512
#define DDIM    64
#define CSTRIDE 16384      // H*W
#define IMG     1048576    // C*H*W
#define BLK     256
#define TOKPB   512        // tokens per block (2 per lane)
#define QOFF    1
#define POFF    16777217
#define EOFF    16777218

__device__ __forceinline__ float np_pairwise_sq64(const float* v) {
    float r[8];
#pragma unroll
    for (int j = 0; j < 8; ++j) r[j] = __fmul_rn(v[j], v[j]);
#pragma unroll
    for (int i = 8; i < 64; i += 8) {
#pragma unroll
        for (int j = 0; j < 8; ++j)
            r[j] = __fadd_rn(r[j], __fmul_rn(v[i + j], v[i + j]));
    }
    float s01 = __fadd_rn(r[0], r[1]);
    float s23 = __fadd_rn(r[2], r[3]);
    float s45 = __fadd_rn(r[4], r[5]);
    float s67 = __fadd_rn(r[6], r[7]);
    return __fadd_rn(__fadd_rn(s01, s23), __fadd_rn(s45, s67));
}

__global__ void vq_bnorm(const float* __restrict__ emb, float* __restrict__ ws) {
    int k = threadIdx.x;                 // 512 threads, 1 block
    const float* e = emb + k * DDIM;
    float v[64];
#pragma unroll
    for (int i = 0; i < 64; ++i) v[i] = e[i];
    ws[512 + k] = np_pairwise_sq64(v);
}

__global__ __launch_bounds__(BLK) void vq_main(const float* __restrict__ in,
                                               const float* __restrict__ emb,
                                               float* __restrict__ out,
                                               float* __restrict__ ws) {
    __shared__ float red[BLK / 64];

    const int tid = threadIdx.x;
    const int blk = blockIdx.x;
    const int tok0 = blk * TOKPB + tid;
    const int tok1 = tok0 + BLK;

    const int b0 = tok0 >> 14, hw0 = tok0 & 16383;
    const int b1 = tok1 >> 14, hw1 = tok1 & 16383;
    const float* p0 = in + (size_t)b0 * IMG + hw0;
    const float* p1 = in + (size_t)b1 * IMG + hw1;

    float x0[64], x1[64];
#pragma unroll
    for (int c = 0; c < 64; ++c) x0[c] = p0[(size_t)c * CSTRIDE];
#pragma unroll
    for (int c = 0; c < 64; ++c) x1[c] = p1[(size_t)c * CSTRIDE];

    const float a0 = np_pairwise_sq64(x0);
    const float a1 = np_pairwise_sq64(x1);

    // encodings zero-fill, paced one float4/lane per k-iter (16 KB/block/iter)
    float4* enc4 = (float4*)(out + EOFF + (size_t)blk * (TOKPB * KCODES));
    const float4 z4 = make_float4(0.f, 0.f, 0.f, 0.f);

    const float* __restrict__ bws = ws + 512;   // uniform -> s_load
    float dmin0 = 3.402823466e38f, dmin1 = 3.402823466e38f;
    int id0 = 0, id1 = 0;

#pragma unroll 1
    for (int k = 0; k < KCODES; ++k) {
        if (k < KCODES / 2) enc4[(size_t)k * BLK + tid] = z4;   // pacing: 256 iters cover 1 MB
        const float bk = bws[k];
        const float* __restrict__ ek = emb + (size_t)k * DDIM;  // uniform -> s_load
        float d0 = 0.f, d1 = 0.f;
#pragma unroll
        for (int d = 0; d < 64; ++d) {
            const float ev = ek[d];
            d0 = fmaf(x0[d], ev, d0);
            d1 = fmaf(x1[d], ev, d1);
        }
        const float t0 = __fadd_rn(a0, bk); const float dd0 = fmaf(-2.0f, d0, t0);
        const float t1 = __fadd_rn(a1, bk); const float dd1 = fmaf(-2.0f, d1, t1);
        if (dd0 < dmin0) { dmin0 = dd0; id0 = k; }
        if (dd1 < dmin1) { dmin1 = dd1; id1 = k; }
    }

    atomicAdd((int*)ws + id0, 1);
    atomicAdd((int*)ws + id1, 1);

    // quantized_st = fl(x + fl(q - x)), NCHW coalesced stores; loss partials
    float lsum = 0.f;
    {
        const float4* e0 = (const float4*)(emb + (size_t)id0 * DDIM);
        float* q0 = out + QOFF + (size_t)b0 * IMG + hw0;
#pragma unroll
        for (int cq = 0; cq < 16; ++cq) {
            float4 q = e0[cq];
            float d;
            d = __fsub_rn(q.x, x0[cq*4+0]); lsum = __fadd_rn(lsum, __fmul_rn(d,d)); q0[(size_t)(cq*4+0)*CSTRIDE] = __fadd_rn(x0[cq*4+0], d);
            d = __fsub_rn(q.y, x0[cq*4+1]); lsum = __fadd_rn(lsum, __fmul_rn(d,d)); q0[(size_t)(cq*4+1)*CSTRIDE] = __fadd_rn(x0[cq*4+1], d);
            d = __fsub_rn(q.z, x0[cq*4+2]); lsum = __fadd_rn(lsum, __fmul_rn(d,d)); q0[(size_t)(cq*4+2)*CSTRIDE] = __fadd_rn(x0[cq*4+2], d);
            d = __fsub_rn(q.w, x0[cq*4+3]); lsum = __fadd_rn(lsum, __fmul_rn(d,d)); q0[(size_t)(cq*4+3)*CSTRIDE] = __fadd_rn(x0[cq*4+3], d);
        }
    }
    {
        const float4* e1 = (const float4*)(emb + (size_t)id1 * DDIM);
        float* q1 = out + QOFF + (size_t)b1 * IMG + hw1;
#pragma unroll
        for (int cq = 0; cq < 16; ++cq) {
            float4 q = e1[cq];
            float d;
            d = __fsub_rn(q.x, x1[cq*4+0]); lsum = __fadd_rn(lsum, __fmul_rn(d,d)); q1[(size_t)(cq*4+0)*CSTRIDE] = __fadd_rn(x1[cq*4+0], d);
            d = __fsub_rn(q.y, x1[cq*4+1]); lsum = __fadd_rn(lsum, __fmul_rn(d,d)); q1[(size_t)(cq*4+1)*CSTRIDE] = __fadd_rn(x1[cq*4+1], d);
            d = __fsub_rn(q.z, x1[cq*4+2]); lsum = __fadd_rn(lsum, __fmul_rn(d,d)); q1[(size_t)(cq*4+2)*CSTRIDE] = __fadd_rn(x1[cq*4+2], d);
            d = __fsub_rn(q.w, x1[cq*4+3]); lsum = __fadd_rn(lsum, __fmul_rn(d,d)); q1[(size_t)(cq*4+3)*CSTRIDE] = __fadd_rn(x1[cq*4+3], d);
        }
    }
#pragma unroll
    for (int off = 32; off > 0; off >>= 1) lsum += __shfl_down(lsum, off);
    if ((tid & 63) == 0) red[tid >> 6] = lsum;

    // barrier: compiler drains vmcnt(0) before s_barrier -> all zero-stores
    // (including to the two hot addresses) are complete before the 1.0 stores
    __syncthreads();
    if (tid == 0) ws[1024 + blk] = red[0] + red[1] + red[2] + red[3];

    out[EOFF + (size_t)tok0 * KCODES + id0] = 1.0f;
    out[EOFF + (size_t)tok1 * KCODES + id1] = 1.0f;
}

__global__ void vq_final(float* __restrict__ out, const float* __restrict__ ws) {
    __shared__ float sl[512], sp[512];
    int t = threadIdx.x;                          // 512 threads, 1 block
    sl[t] = ws[1024 + t];
    int cnt = ((const int*)ws)[t];
    float p = (float)cnt * (1.0f / 262144.0f);
    sp[t] = p * logf(p + 1e-10f);
    __syncthreads();
    for (int off = 256; off > 0; off >>= 1) {
        if (t < off) { sl[t] += sl[t + off]; sp[t] += sp[t + off]; }
        __syncthreads();
    }
    if (t == 0) {
        float m = sl[0] * (1.0f / 16777216.0f);   // /2^24 exact
        out[0]    = __fadd_rn(m, __fmul_rn(0.25f, m));  // q_latent + 0.25*e_latent
        out[POFF] = expf(-sp[0]);
    }
}

extern "C" void kernel_launch(void* const* d_in, const int* in_sizes, int n_in,
                              void* d_out, int out_size, void* d_ws, size_t ws_size,
                              hipStream_t stream) {
    const float* in  = (const float*)d_in[0];
    const float* emb = (const float*)d_in[1];
    float* out = (float*)d_out;
    float* ws  = (float*)d_ws;

    hipMemsetAsync(d_ws, 0, 512 * sizeof(int), stream);          // histogram
    hipLaunchKernelGGL(vq_bnorm, dim3(1),   dim3(512), 0, stream, emb, ws);
    hipLaunchKernelGGL(vq_main,  dim3(512), dim3(BLK), 0, stream, in, emb, out, ws);
    hipLaunchKernelGGL(vq_final, dim3(1),   dim3(512), 0, stream, out, ws);
}

// Round 3
// 1097.219 us; speedup vs baseline: 1.1465x; 1.1465x over previous
//
#include <hip/hip_runtime.h>
#include <math.h>

// VQ-VAE quantizer. Outputs in d_out (float32, flat, concat):
//   [0]                       loss
//   [1 .. 16777216]           quantized_st, NCHW [16,64,128,128]
//   [16777217]                perplexity
//   [16777218 .. +134217728)  encodings one-hot [262144, 512]
//
// R3 structure: two-phase.
//   vq_dist (1024 blocks): split-k=2. Block (pair,half) scans 256 codes for
//     512 tokens with the R1 LDS-broadcast FMA loop; writes (dmin,idx) into
//     a 2048-float header at the front of each 512 KB encodings sub-region
//     (scratch that vq_emit overwrites after reading).
//   vq_emit (1024 blocks): pure streaming. Winner = (ddB < ddA) ? idxB : idxA
//     (strict < keeps np.argmin first-occurrence across halves). Writes
//     quantized_st + one-hot rows (1.0 inline) + hist + loss partials.
//
// Numerics (bit-exact vs np, verified absmax 0.0 in R1/R2): numpy pairwise
// 8-accumulator sums for ||x||^2,||e||^2; sequential fp32 FMA chain for the
// dot; d = fma(-2,dot,fl(a+b)); strict < ascending-k scan.
//
// ws (floats): [0..511] hist(int), [512..1023] b_k, [1024..2047] loss partials.

#define NTOK    262144
#define KCODES  512
#define DDIM    64
#define CSTRIDE 16384      // H*W
#define IMG     1048576    // C*H*W
#define QOFF    1
#define POFF    16777217
#define EOFF    16777218
#define SUBFLT  131072     // floats per encodings sub-region (256 rows)

__device__ __forceinline__ float np_pairwise_sq64(const float* v) {
    float r[8];
#pragma unroll
    for (int j = 0; j < 8; ++j) r[j] = __fmul_rn(v[j], v[j]);
#pragma unroll
    for (int i = 8; i < 64; i += 8) {
#pragma unroll
        for (int j = 0; j < 8; ++j)
            r[j] = __fadd_rn(r[j], __fmul_rn(v[i + j], v[i + j]));
    }
    float s01 = __fadd_rn(r[0], r[1]);
    float s23 = __fadd_rn(r[2], r[3]);
    float s45 = __fadd_rn(r[4], r[5]);
    float s67 = __fadd_rn(r[6], r[7]);
    return __fadd_rn(__fadd_rn(s01, s23), __fadd_rn(s45, s67));
}

__global__ void vq_bnorm(const float* __restrict__ emb, float* __restrict__ ws) {
    int k = threadIdx.x;                 // 512 threads, 1 block
    const float* e = emb + k * DDIM;
    float v[64];
#pragma unroll
    for (int i = 0; i < 64; ++i) v[i] = e[i];
    ws[512 + k] = np_pairwise_sq64(v);
}

// ---- phase 1: distances + per-half argmin -------------------------------
__global__ __launch_bounds__(256, 3) void vq_dist(const float* __restrict__ in,
                                                  const float* __restrict__ emb,
                                                  float* __restrict__ out,
                                                  const float* __restrict__ ws) {
    __shared__ float4 et4[64 * 32];      // e^T chunk: [d][128 codes], 32 KB
    __shared__ float  bsh[256];

    float* et = (float*)et4;
    const int tid   = threadIdx.x;
    const int pair  = blockIdx.x >> 1;
    const int half  = blockIdx.x & 1;
    const int kbase = half * 256;

    const int tok0 = pair * 512 + tid;
    const int tok1 = tok0 + 256;

    bsh[tid] = ws[512 + kbase + tid];

    const int b0 = tok0 >> 14, hw0 = tok0 & 16383;
    const int b1 = tok1 >> 14, hw1 = tok1 & 16383;
    const float* p0 = in + (size_t)b0 * IMG + hw0;
    const float* p1 = in + (size_t)b1 * IMG + hw1;

    float x0[64], x1[64];
#pragma unroll
    for (int c = 0; c < 64; ++c) x0[c] = p0[(size_t)c * CSTRIDE];
#pragma unroll
    for (int c = 0; c < 64; ++c) x1[c] = p1[(size_t)c * CSTRIDE];

    const float a0 = np_pairwise_sq64(x0);
    const float a1 = np_pairwise_sq64(x1);

    float dmin0 = 3.402823466e38f, dmin1 = 3.402823466e38f;
    int id0 = 0, id1 = 0;

    for (int kc = 0; kc < 2; ++kc) {
        __syncthreads();
        // stage 128 codes transposed into LDS (coalesced float4 reads)
#pragma unroll
        for (int j = 0; j < 8; ++j) {
            int t  = tid + j * 256;      // 0..2047
            int k  = t >> 4;             // code within chunk
            int dq = t & 15;             // float4 index along d
            float4 g = ((const float4*)emb)[(size_t)(kbase + kc * 128 + k) * 16 + dq];
            et[(dq * 4 + 0) * 128 + k] = g.x;
            et[(dq * 4 + 1) * 128 + k] = g.y;
            et[(dq * 4 + 2) * 128 + k] = g.z;
            et[(dq * 4 + 3) * 128 + k] = g.w;
        }
        __syncthreads();

        for (int kg = 0; kg < 32; ++kg) {
            float a00 = 0.f, a01 = 0.f, a02 = 0.f, a03 = 0.f;
            float a10 = 0.f, a11 = 0.f, a12 = 0.f, a13 = 0.f;
#pragma unroll
            for (int d = 0; d < 64; ++d) {
                const float4 ev = et4[d * 32 + kg];   // broadcast read
                a00 = fmaf(x0[d], ev.x, a00);
                a01 = fmaf(x0[d], ev.y, a01);
                a02 = fmaf(x0[d], ev.z, a02);
                a03 = fmaf(x0[d], ev.w, a03);
                a10 = fmaf(x1[d], ev.x, a10);
                a11 = fmaf(x1[d], ev.y, a11);
                a12 = fmaf(x1[d], ev.z, a12);
                a13 = fmaf(x1[d], ev.w, a13);
            }
            const int kb = kc * 128 + kg * 4;         // local 0..255
            {
                float t = __fadd_rn(a0, bsh[kb + 0]); float dd = fmaf(-2.0f, a00, t);
                if (dd < dmin0) { dmin0 = dd; id0 = kb + 0; }
                t = __fadd_rn(a0, bsh[kb + 1]); dd = fmaf(-2.0f, a01, t);
                if (dd < dmin0) { dmin0 = dd; id0 = kb + 1; }
                t = __fadd_rn(a0, bsh[kb + 2]); dd = fmaf(-2.0f, a02, t);
                if (dd < dmin0) { dmin0 = dd; id0 = kb + 2; }
                t = __fadd_rn(a0, bsh[kb + 3]); dd = fmaf(-2.0f, a03, t);
                if (dd < dmin0) { dmin0 = dd; id0 = kb + 3; }
            }
            {
                float t = __fadd_rn(a1, bsh[kb + 0]); float dd = fmaf(-2.0f, a10, t);
                if (dd < dmin1) { dmin1 = dd; id1 = kb + 0; }
                t = __fadd_rn(a1, bsh[kb + 1]); dd = fmaf(-2.0f, a11, t);
                if (dd < dmin1) { dmin1 = dd; id1 = kb + 1; }
                t = __fadd_rn(a1, bsh[kb + 2]); dd = fmaf(-2.0f, a12, t);
                if (dd < dmin1) { dmin1 = dd; id1 = kb + 2; }
                t = __fadd_rn(a1, bsh[kb + 3]); dd = fmaf(-2.0f, a13, t);
                if (dd < dmin1) { dmin1 = dd; id1 = kb + 3; }
            }
        }
    }

    // header layout per 512 KB sub-region (floats):
    //   [0..255]   dd  half0   [256..511] dd  half1
    //   [512..767] idx half0   [768..1023] idx half1   (as ints)
    float* hdr0 = out + EOFF + (size_t)pair * 262144;            // sub 0 (tok0)
    float* hdr1 = hdr0 + SUBFLT;                                 // sub 1 (tok1)
    hdr0[half * 256 + tid] = dmin0;
    ((int*)hdr0)[512 + half * 256 + tid] = kbase + id0;
    hdr1[half * 256 + tid] = dmin1;
    ((int*)hdr1)[512 + half * 256 + tid] = kbase + id1;
}

// ---- phase 2: combine + all output streams ------------------------------
__global__ __launch_bounds__(256) void vq_emit(const float* __restrict__ in,
                                               const float* __restrict__ emb,
                                               float* __restrict__ out,
                                               float* __restrict__ ws) {
    __shared__ int   idx_sh[256];
    __shared__ float red[4];
    const int tid = threadIdx.x;
    const int p   = blockIdx.x >> 1;
    const int s   = blockIdx.x & 1;

    float* sub = out + EOFF + (size_t)p * 262144 + (size_t)s * SUBFLT;
    const int* isub = (const int*)sub;

    const float dA = sub[tid];
    const float dB = sub[256 + tid];
    const int   iA = isub[512 + tid];
    const int   iB = isub[768 + tid];
    const int   id = (dB < dA) ? iB : iA;   // strict <: np first-occurrence
    idx_sh[tid] = id;
    atomicAdd((int*)ws + id, 1);

    const int tok = p * 512 + s * 256 + tid;
    const int b = tok >> 14, hw = tok & 16383;
    const float* px = in + (size_t)b * IMG + hw;
    float*       q  = out + QOFF + (size_t)b * IMG + hw;
    const float4* e0 = (const float4*)(emb + (size_t)id * DDIM);

    float lsum = 0.f;
#pragma unroll
    for (int cq = 0; cq < 16; ++cq) {
        float4 qv = e0[cq];
        float x, d;
        x = px[(size_t)(cq*4+0)*CSTRIDE]; d = __fsub_rn(qv.x, x); lsum = __fadd_rn(lsum, __fmul_rn(d,d)); q[(size_t)(cq*4+0)*CSTRIDE] = __fadd_rn(x, d);
        x = px[(size_t)(cq*4+1)*CSTRIDE]; d = __fsub_rn(qv.y, x); lsum = __fadd_rn(lsum, __fmul_rn(d,d)); q[(size_t)(cq*4+1)*CSTRIDE] = __fadd_rn(x, d);
        x = px[(size_t)(cq*4+2)*CSTRIDE]; d = __fsub_rn(qv.z, x); lsum = __fadd_rn(lsum, __fmul_rn(d,d)); q[(size_t)(cq*4+2)*CSTRIDE] = __fadd_rn(x, d);
        x = px[(size_t)(cq*4+3)*CSTRIDE]; d = __fsub_rn(qv.w, x); lsum = __fadd_rn(lsum, __fmul_rn(d,d)); q[(size_t)(cq*4+3)*CSTRIDE] = __fadd_rn(x, d);
    }
#pragma unroll
    for (int off = 32; off > 0; off >>= 1) lsum += __shfl_down(lsum, off);
    if ((tid & 63) == 0) red[tid >> 6] = lsum;

    // barrier: idx_sh ready AND all header reads retired before overwrite
    __syncthreads();
    if (tid == 0) ws[1024 + blockIdx.x] = red[0] + red[1] + red[2] + red[3];

    // one-hot fill, 512 KB contiguous, 1.0 written inline
    float4* e4 = (float4*)sub;
#pragma unroll 4
    for (int i = 0; i < 128; ++i) {
        int j  = i * 256 + tid;          // float4 index in sub-region
        int ix = idx_sh[j >> 7];         // row = j>>7 (128 float4 per row)
        int c0 = (j & 127) << 2;
        float4 v;
        v.x = (c0     == ix) ? 1.0f : 0.0f;
        v.y = (c0 + 1 == ix) ? 1.0f : 0.0f;
        v.z = (c0 + 2 == ix) ? 1.0f : 0.0f;
        v.w = (c0 + 3 == ix) ? 1.0f : 0.0f;
        e4[j] = v;
    }
}

__global__ void vq_final(float* __restrict__ out, const float* __restrict__ ws) {
    __shared__ float sl[512], sp[512];
    int t = threadIdx.x;                          // 512 threads, 1 block
    sl[t] = ws[1024 + t] + ws[1536 + t];          // 1024 loss partials
    int cnt = ((const int*)ws)[t];
    float p = (float)cnt * (1.0f / 262144.0f);
    sp[t] = p * logf(p + 1e-10f);
    __syncthreads();
    for (int off = 256; off > 0; off >>= 1) {
        if (t < off) { sl[t] += sl[t + off]; sp[t] += sp[t + off]; }
        __syncthreads();
    }
    if (t == 0) {
        float m = sl[0] * (1.0f / 16777216.0f);   // /2^24 exact
        out[0]    = __fadd_rn(m, __fmul_rn(0.25f, m));  // q + 0.25*e latent
        out[POFF] = expf(-sp[0]);
    }
}

extern "C" void kernel_launch(void* const* d_in, const int* in_sizes, int n_in,
                              void* d_out, int out_size, void* d_ws, size_t ws_size,
                              hipStream_t stream) {
    const float* in  = (const float*)d_in[0];
    const float* emb = (const float*)d_in[1];
    float* out = (float*)d_out;
    float* ws  = (float*)d_ws;

    hipMemsetAsync(d_ws, 0, 512 * sizeof(int), stream);          // histogram
    hipLaunchKernelGGL(vq_bnorm, dim3(1),    dim3(512), 0, stream, emb, ws);
    hipLaunchKernelGGL(vq_dist,  dim3(1024), dim3(256), 0, stream, in, emb, out, ws);
    hipLaunchKernelGGL(vq_emit,  dim3(1024), dim3(256), 0, stream, in, emb, out, ws);
    hipLaunchKernelGGL(vq_final, dim3(1),    dim3(512), 0, stream, out, ws);
}

// Round 4
// 971.341 us; speedup vs baseline: 1.2950x; 1.1296x over previous
//
#include <hip/hip_runtime.h>
#include <math.h>

// VQ-VAE quantizer. Outputs in d_out (float32, flat, concat):
//   [0] loss | [1..16777216] quantized_st NCHW | [16777217] perplexity
//   [16777218 ..) encodings one-hot [262144,512]
//
// R4: GEMM-style register tiling for the distance phase.
//   vq_prep: a_tok = ||x||^2 (np-pairwise exact) -> scratch in quantized
//            region; b_k = ||e_k||^2 -> ws; e^T [64][512] -> scratch.
//   vq_dist (2048 blocks): tile 128 tokens x 128 codes, lane=(i,j) 16x16,
//            8x8 acc/lane, x-tile & e-tile in LDS, 4 ds_read_b128 : 64 FMA.
//            Per-lane argmin over 4 chunks, shfl_xor cross-j merge
//            ((==, smaller idx) = np first-occurrence). idx -> 128-int
//            header per 256KB encodings sub-region.
//   vq_emit (2048 blocks): streaming quantized_st + one-hot + hist + loss.
//
// Numerics bit-exact vs np (absmax 0.0 in R1-R3): np pairwise 8-acc sums for
// norms; sequential fp32 FMA chain over d for the dot; dd=fma(-2,dot,fl(a+b));
// ascending-code strict < argmin.
//
// ws (floats): [0..511] hist(int), [512..1023] b_k, [1024..3071] loss partials.

#define NTOK    262144
#define KCODES  512
#define DDIM    64
#define CSTRIDE 16384
#define IMG     1048576
#define QOFF    1
#define POFF    16777217
#define EOFF    16777218
#define SA      4          // a-norm scratch base (quantized region, 16B-aligned)
#define SE      262148     // e^T scratch base
#define SUBROW  65536      // floats per emit sub-region (128 rows x 512)

__device__ __forceinline__ float np_pairwise_sq64(const float* v) {
    float r[8];
#pragma unroll
    for (int j = 0; j < 8; ++j) r[j] = __fmul_rn(v[j], v[j]);
#pragma unroll
    for (int i = 8; i < 64; i += 8) {
#pragma unroll
        for (int j = 0; j < 8; ++j)
            r[j] = __fadd_rn(r[j], __fmul_rn(v[i + j], v[i + j]));
    }
    float s01 = __fadd_rn(r[0], r[1]);
    float s23 = __fadd_rn(r[2], r[3]);
    float s45 = __fadd_rn(r[4], r[5]);
    float s67 = __fadd_rn(r[6], r[7]);
    return __fadd_rn(__fadd_rn(s01, s23), __fadd_rn(s45, s67));
}

// blocks 0..1023: a-norms for all tokens; block 1024: b_k + e^T
__global__ __launch_bounds__(256) void vq_prep(const float* __restrict__ in,
                                               const float* __restrict__ emb,
                                               float* __restrict__ out,
                                               float* __restrict__ ws) {
    const int tid = threadIdx.x, blk = blockIdx.x;
    if (blk < 1024) {
        const int tok = blk * 256 + tid;
        const int b = tok >> 14, hw = tok & 16383;
        const float* p = in + (size_t)b * IMG + hw;
        float v[64];
#pragma unroll
        for (int c = 0; c < 64; ++c) v[c] = p[(size_t)c * CSTRIDE];
        out[SA + tok] = np_pairwise_sq64(v);
    } else {
#pragma unroll
        for (int r = 0; r < 2; ++r) {
            const int k = tid * 2 + r;
            const float* e = emb + (size_t)k * DDIM;
            float v[64];
#pragma unroll
            for (int i = 0; i < 64; ++i) v[i] = e[i];
            ws[512 + k] = np_pairwise_sq64(v);
        }
        for (int t = tid; t < 32768; t += 256) {         // e^T[d][k]
            int d = t >> 9, k = t & 511;
            out[SE + t] = emb[(size_t)k * DDIM + d];
        }
    }
}

// ---- distance phase: 128 tok x 512 codes per block, 8x8 register tile ----
__global__ __launch_bounds__(256, 2) void vq_dist(const float* __restrict__ in,
                                                  float* __restrict__ out,
                                                  const float* __restrict__ ws) {
    __shared__ float4 xs4[2048];     // x-tile  [64 d][32 float4] = 32 KB
    __shared__ float4 es4[2048];     // e-chunk [64 d][32 float4] = 32 KB

    const int tid = threadIdx.x, blk = blockIdx.x;
    const int i = tid >> 4, j = tid & 15;            // 16x16 lane grid
    const int T0 = blk * 128, b = T0 >> 14, hw0 = T0 & 16383;

    {   // stage x-tile: input is NCHW == [d][token] already; conflict-free b128
        const float4* gx = (const float4*)(in + (size_t)b * IMG + hw0);
#pragma unroll
        for (int jj = 0; jj < 8; ++jj) {
            int t = tid + jj * 256;                  // t = c*32 + q
            int c = t >> 5, q = t & 31;
            xs4[t] = gx[(size_t)c * (CSTRIDE / 4) + q];
        }
    }

    float av[8];
    {
        const float4* ap = (const float4*)(out + SA + T0 + 8 * i);
        float4 u0 = ap[0], u1 = ap[1];
        av[0]=u0.x; av[1]=u0.y; av[2]=u0.z; av[3]=u0.w;
        av[4]=u1.x; av[5]=u1.y; av[6]=u1.z; av[7]=u1.w;
    }

    float dmin[8]; int idx[8];
#pragma unroll
    for (int tt = 0; tt < 8; ++tt) { dmin[tt] = 3.402823466e38f; idx[tt] = 0; }

    for (int ch = 0; ch < 4; ++ch) {
        __syncthreads();
        {   // stage e-chunk from e^T scratch (rows of 512B, coalesced)
            const float4* ge = (const float4*)(out + SE + ch * 128);
#pragma unroll
            for (int jj = 0; jj < 8; ++jj) {
                int t = tid + jj * 256;
                int d = t >> 5, q = t & 31;
                es4[t] = ge[(size_t)d * 128 + q];
            }
        }
        __syncthreads();

        float acc[8][8];
#pragma unroll
        for (int tt = 0; tt < 8; ++tt)
#pragma unroll
            for (int cc = 0; cc < 8; ++cc) acc[tt][cc] = 0.f;

        const float4* xr = xs4 + 2 * i;
        const float4* er = es4 + 2 * j;
#pragma unroll 4
        for (int d = 0; d < 64; ++d) {
            float4 xa = xr[d * 32], xb = xr[d * 32 + 1];
            float4 ea = er[d * 32], eb = er[d * 32 + 1];
            float xv[8] = {xa.x,xa.y,xa.z,xa.w,xb.x,xb.y,xb.z,xb.w};
            float ev[8] = {ea.x,ea.y,ea.z,ea.w,eb.x,eb.y,eb.z,eb.w};
#pragma unroll
            for (int tt = 0; tt < 8; ++tt)
#pragma unroll
                for (int cc = 0; cc < 8; ++cc)
                    acc[tt][cc] = fmaf(xv[tt], ev[cc], acc[tt][cc]);
        }

        float bk[8];
        {
            const float4* bp = (const float4*)(ws + 512 + ch * 128 + 8 * j);
            float4 u0 = bp[0], u1 = bp[1];
            bk[0]=u0.x; bk[1]=u0.y; bk[2]=u0.z; bk[3]=u0.w;
            bk[4]=u1.x; bk[5]=u1.y; bk[6]=u1.z; bk[7]=u1.w;
        }
        const int cbase = ch * 128 + 8 * j;
#pragma unroll
        for (int cc = 0; cc < 8; ++cc) {                 // ascending code per tt
#pragma unroll
            for (int tt = 0; tt < 8; ++tt) {
                float t2 = __fadd_rn(av[tt], bk[cc]);
                float dd = fmaf(-2.0f, acc[tt][cc], t2);
                if (dd < dmin[tt]) { dmin[tt] = dd; idx[tt] = cbase + cc; }
            }
        }
    }

    // cross-j merge (lanes differing in bits 0..3 = same 8 tokens)
#pragma unroll
    for (int m = 1; m < 16; m <<= 1) {
#pragma unroll
        for (int tt = 0; tt < 8; ++tt) {
            float od = __shfl_xor(dmin[tt], m, 64);
            int   oi = __shfl_xor(idx[tt],  m, 64);
            if (od < dmin[tt] || (od == dmin[tt] && oi < idx[tt])) {
                dmin[tt] = od; idx[tt] = oi;
            }
        }
    }
    if (j == 0) {
        int* hdr = (int*)(out + EOFF + (size_t)blk * SUBROW);
#pragma unroll
        for (int tt = 0; tt < 8; ++tt) hdr[8 * i + tt] = idx[tt];
    }
}

// ---- emit phase: quantized_st + one-hot + hist + loss --------------------
__global__ __launch_bounds__(256) void vq_emit(const float* __restrict__ in,
                                               const float* __restrict__ emb,
                                               float* __restrict__ out,
                                               float* __restrict__ ws) {
    __shared__ int   idx_sh[128];
    __shared__ float red[4];
    const int tid = threadIdx.x, blk = blockIdx.x;
    float* sub = out + EOFF + (size_t)blk * SUBROW;

    if (tid < 128) idx_sh[tid] = ((const int*)sub)[tid];
    __syncthreads();

    const int T0 = blk * 128, b = T0 >> 14, hw0 = T0 & 16383;
    const int tl = tid & 127, ch = (tid >> 7) * 32;   // 2 lanes per token
    const int id = idx_sh[tl];
    if (tid < 128) atomicAdd((int*)ws + id, 1);

    const float* px = in  + (size_t)b * IMG + hw0 + tl;
    float*       q  = out + QOFF + (size_t)b * IMG + hw0 + tl;
    const float* e0 = emb + (size_t)id * DDIM + ch;

    float lsum = 0.f;
#pragma unroll
    for (int cc = 0; cc < 32; ++cc) {
        float x   = px[(size_t)(ch + cc) * CSTRIDE];
        float dqx = __fsub_rn(e0[cc], x);
        lsum = __fadd_rn(lsum, __fmul_rn(dqx, dqx));
        q[(size_t)(ch + cc) * CSTRIDE] = __fadd_rn(x, dqx);
    }
#pragma unroll
    for (int off = 32; off > 0; off >>= 1) lsum += __shfl_down(lsum, off, 64);
    if ((tid & 63) == 0) red[tid >> 6] = lsum;
    __syncthreads();
    if (tid == 0) ws[1024 + blk] = red[0] + red[1] + red[2] + red[3];

    // one-hot fill, 256 KB contiguous, 1.0 inline (header already consumed)
    float4* s4 = (float4*)sub;
#pragma unroll 4
    for (int ii = 0; ii < 64; ++ii) {
        int jj  = ii * 256 + tid;        // float4 index; 128 float4 per row
        int ix  = idx_sh[jj >> 7];
        int c0  = (jj & 127) << 2;
        float4 v;
        v.x = (c0     == ix) ? 1.0f : 0.0f;
        v.y = (c0 + 1 == ix) ? 1.0f : 0.0f;
        v.z = (c0 + 2 == ix) ? 1.0f : 0.0f;
        v.w = (c0 + 3 == ix) ? 1.0f : 0.0f;
        s4[jj] = v;
    }
}

__global__ void vq_final(float* __restrict__ out, const float* __restrict__ ws) {
    __shared__ float sl[512], sp[512];
    int t = threadIdx.x;                              // 512 threads, 1 block
    sl[t] = ws[1024 + t] + ws[1536 + t] + ws[2048 + t] + ws[2560 + t];
    int cnt = ((const int*)ws)[t];
    float p = (float)cnt * (1.0f / 262144.0f);
    sp[t] = p * logf(p + 1e-10f);
    __syncthreads();
    for (int off = 256; off > 0; off >>= 1) {
        if (t < off) { sl[t] += sl[t + off]; sp[t] += sp[t + off]; }
        __syncthreads();
    }
    if (t == 0) {
        float m = sl[0] * (1.0f / 16777216.0f);       // /2^24 exact
        out[0]    = __fadd_rn(m, __fmul_rn(0.25f, m));
        out[POFF] = expf(-sp[0]);
    }
}

extern "C" void kernel_launch(void* const* d_in, const int* in_sizes, int n_in,
                              void* d_out, int out_size, void* d_ws, size_t ws_size,
                              hipStream_t stream) {
    const float* in  = (const float*)d_in[0];
    const float* emb = (const float*)d_in[1];
    float* out = (float*)d_out;
    float* ws  = (float*)d_ws;

    hipMemsetAsync(d_ws, 0, 512 * sizeof(int), stream);            // histogram
    hipLaunchKernelGGL(vq_prep,  dim3(1025), dim3(256), 0, stream, in, emb, out, ws);
    hipLaunchKernelGGL(vq_dist,  dim3(2048), dim3(256), 0, stream, in, out, ws);
    hipLaunchKernelGGL(vq_emit,  dim3(2048), dim3(256), 0, stream, in, emb, out, ws);
    hipLaunchKernelGGL(vq_final, dim3(1),    dim3(512), 0, stream, out, ws);
}

// Round 6
// 770.375 us; speedup vs baseline: 1.6329x; 1.2609x over previous
//
#include <hip/hip_runtime.h>
#include <math.h>

// VQ-VAE quantizer. Outputs in d_out (float32, flat, concat):
//   [0] loss | [1..16777216] quantized_st NCHW | [16777217] perplexity
//   [16777218 ..) encodings one-hot [262144,512]
//
// R6 = R5 fused structure, with the e^T scratch moved from the quantized
// output region into d_ws. R5's failure: fused blocks wrote quantized values
// over out[SE..] (e^T) while other blocks were still staging e-chunks from
// it -> corrupted distances -> perplexity off. ws is private scratch with no
// concurrent consumer -> race gone.
//
//   vq_prep (9 blocks): e^T [64][512] -> ws[4096..36863]; b_k -> ws[512..1023].
//   vq_main (2048 blocks x 256 thr, 64KB LDS, 2 blk/CU): per block
//     (128 tokens): stage x-tile [64d][128tok] (NCHW already [d][tok]);
//     ||x||^2 from LDS (np-pairwise exact); 4 e-chunks with 8x8 register FMA
//     tile (16 FMA : 1 ds_read_b128) + fire-and-forget one-hot ZERO stores
//     (drained by pre-barrier vmcnt(0) -> ordered before 1.0 fixups, pattern
//     validated bit-exact in R2); shfl_xor argmin merge ((==, smaller idx) =
//     np first-occurrence); epilogue: hist, quantized_st (x from LDS), loss,
//     one-hot 1.0 fixups.
//
// Numerics bit-exact vs np (absmax 0.0 R1-R4): np pairwise 8-acc sums for
// norms; sequential fp32 FMA chain over d; dd=fma(-2,dot,fl(a+b));
// ascending-code strict < argmin.
//
// ws (floats): [0..511] hist(int), [512..1023] b_k,
//              [1024..3071] loss partials, [4096..36863] e^T. (148 KB used)

#define NTOK    262144
#define KCODES  512
#define DDIM    64
#define CSTRIDE 16384
#define IMG     1048576
#define QOFF    1
#define POFF    16777217
#define EOFF    16777218
#define EWS     4096       // e^T base in ws (floats)
#define SUBROW  65536      // floats per one-hot sub-region (128 rows x 512)

__device__ __forceinline__ float np_pairwise_sq64(const float* v) {
    float r[8];
#pragma unroll
    for (int j = 0; j < 8; ++j) r[j] = __fmul_rn(v[j], v[j]);
#pragma unroll
    for (int i = 8; i < 64; i += 8) {
#pragma unroll
        for (int j = 0; j < 8; ++j)
            r[j] = __fadd_rn(r[j], __fmul_rn(v[i + j], v[i + j]));
    }
    float s01 = __fadd_rn(r[0], r[1]);
    float s23 = __fadd_rn(r[2], r[3]);
    float s45 = __fadd_rn(r[4], r[5]);
    float s67 = __fadd_rn(r[6], r[7]);
    return __fadd_rn(__fadd_rn(s01, s23), __fadd_rn(s45, s67));
}

// blocks 0..7: e^T [64][512] -> ws[EWS..]; block 8: b_k -> ws[512..1023]
__global__ __launch_bounds__(256) void vq_prep(const float* __restrict__ emb,
                                               float* __restrict__ ws) {
    const int tid = threadIdx.x, blk = blockIdx.x;
    if (blk < 8) {
#pragma unroll
        for (int ii = 0; ii < 16; ++ii) {
            int t = blk * 4096 + ii * 256 + tid;     // t = d*512 + k
            ws[EWS + t] = emb[(size_t)(t & 511) * DDIM + (t >> 9)];
        }
    } else {
#pragma unroll
        for (int r = 0; r < 2; ++r) {
            const int k = tid * 2 + r;
            const float* e = emb + (size_t)k * DDIM;
            float v[64];
#pragma unroll
            for (int i = 0; i < 64; ++i) v[i] = e[i];
            ws[512 + k] = np_pairwise_sq64(v);
        }
    }
}

// ---- fused main: distances + argmin + all output streams ----------------
__global__ __launch_bounds__(256, 2) void vq_main(const float* __restrict__ in,
                                                  const float* __restrict__ emb,
                                                  float* __restrict__ out,
                                                  float* __restrict__ ws) {
    __shared__ float4 xs4[2048];     // x-tile  [64 d][32 float4] = 32 KB
    __shared__ float4 es4[2048];     // e-chunk [64 d][32 float4] = 32 KB
    __shared__ float  ash[128];      // per-token ||x||^2
    __shared__ int    idx_sh[128];
    __shared__ float  red[4];

    const float* xsf = (const float*)xs4;
    const int tid = threadIdx.x, blk = blockIdx.x;
    const int i = tid >> 4, j = tid & 15;            // 16x16 lane grid
    const int T0 = blk * 128, b = T0 >> 14, hw0 = T0 & 16383;

    {   // stage x-tile (conflict-free b128 writes; coalesced global reads)
        const float4* gx = (const float4*)(in + (size_t)b * IMG + hw0);
#pragma unroll
        for (int jj = 0; jj < 8; ++jj) {
            int t = tid + jj * 256;                  // t = c*32 + q
            int c = t >> 5, q = t & 31;
            xs4[t] = gx[(size_t)c * (CSTRIDE / 4) + q];
        }
    }
    __syncthreads();

    if (tid < 128) {                                 // exact per-token norms
        float v[64];
#pragma unroll
        for (int c = 0; c < 64; ++c) v[c] = xsf[c * 128 + tid];
        ash[tid] = np_pairwise_sq64(v);
    }
    // ash visibility covered by the first chunk barrier below

    float av[8];
    float dmin[8]; int idx[8];

    float4* sub4 = (float4*)(out + EOFF + (size_t)blk * SUBROW);
    const float4 z4 = make_float4(0.f, 0.f, 0.f, 0.f);

    for (int ch = 0; ch < 4; ++ch) {
        __syncthreads();
        {   // stage e-chunk from e^T scratch in ws (coalesced)
            const float4* ge = (const float4*)(ws + EWS + ch * 128);
#pragma unroll
            for (int jj = 0; jj < 8; ++jj) {
                int t = tid + jj * 256;
                int d = t >> 5, q = t & 31;
                es4[t] = ge[(size_t)d * 128 + q];
            }
        }
        __syncthreads();

        if (ch == 0) {
#pragma unroll
            for (int tt = 0; tt < 8; ++tt) {
                av[tt] = ash[8 * i + tt];
                dmin[tt] = 3.402823466e38f; idx[tt] = 0;
            }
        }

        // one-hot zero stream: 64 KB/chunk, fire-and-forget (drained by the
        // next chunk's pre-barrier vmcnt(0), long before the 1.0 fixups)
#pragma unroll
        for (int ii = 0; ii < 16; ++ii)
            sub4[ch * 4096 + ii * 256 + tid] = z4;

        float acc[8][8];
#pragma unroll
        for (int tt = 0; tt < 8; ++tt)
#pragma unroll
            for (int cc = 0; cc < 8; ++cc) acc[tt][cc] = 0.f;

        const float4* xr = xs4 + 2 * i;
        const float4* er = es4 + 2 * j;
#pragma unroll 4
        for (int d = 0; d < 64; ++d) {
            float4 xa = xr[d * 32], xb = xr[d * 32 + 1];
            float4 ea = er[d * 32], eb = er[d * 32 + 1];
            float xv[8] = {xa.x,xa.y,xa.z,xa.w,xb.x,xb.y,xb.z,xb.w};
            float ev[8] = {ea.x,ea.y,ea.z,ea.w,eb.x,eb.y,eb.z,eb.w};
#pragma unroll
            for (int tt = 0; tt < 8; ++tt)
#pragma unroll
                for (int cc = 0; cc < 8; ++cc)
                    acc[tt][cc] = fmaf(xv[tt], ev[cc], acc[tt][cc]);
        }

        float bk[8];
        {
            const float4* bp = (const float4*)(ws + 512 + ch * 128 + 8 * j);
            float4 u0 = bp[0], u1 = bp[1];
            bk[0]=u0.x; bk[1]=u0.y; bk[2]=u0.z; bk[3]=u0.w;
            bk[4]=u1.x; bk[5]=u1.y; bk[6]=u1.z; bk[7]=u1.w;
        }
        const int cbase = ch * 128 + 8 * j;
#pragma unroll
        for (int cc = 0; cc < 8; ++cc) {             // ascending code per tt
#pragma unroll
            for (int tt = 0; tt < 8; ++tt) {
                float t2 = __fadd_rn(av[tt], bk[cc]);
                float dd = fmaf(-2.0f, acc[tt][cc], t2);
                if (dd < dmin[tt]) { dmin[tt] = dd; idx[tt] = cbase + cc; }
            }
        }
    }

    // cross-j merge (lanes differing in bits 0..3 = same 8 tokens)
#pragma unroll
    for (int m = 1; m < 16; m <<= 1) {
#pragma unroll
        for (int tt = 0; tt < 8; ++tt) {
            float od = __shfl_xor(dmin[tt], m, 64);
            int   oi = __shfl_xor(idx[tt],  m, 64);
            if (od < dmin[tt] || (od == dmin[tt] && oi < idx[tt])) {
                dmin[tt] = od; idx[tt] = oi;
            }
        }
    }
    if (j == 0) {
#pragma unroll
        for (int tt = 0; tt < 8; ++tt) idx_sh[8 * i + tt] = idx[tt];
    }
    __syncthreads();   // idx_sh ready; all zero-stores drained (vmcnt(0))

    // epilogue: hist, quantized_st (x from LDS), loss
    const int tl = tid & 127, chh = (tid >> 7) * 32;  // 2 lanes per token
    const int id = idx_sh[tl];
    if (tid < 128) atomicAdd((int*)ws + id, 1);

    float*       q  = out + QOFF + (size_t)b * IMG + hw0 + tl;
    const float* e0 = emb + (size_t)id * DDIM + chh;

    float lsum = 0.f;
#pragma unroll
    for (int cc = 0; cc < 32; ++cc) {
        float x   = xsf[(chh + cc) * 128 + tl];
        float dqx = __fsub_rn(e0[cc], x);
        lsum = __fadd_rn(lsum, __fmul_rn(dqx, dqx));
        q[(size_t)(chh + cc) * CSTRIDE] = __fadd_rn(x, dqx);
    }
#pragma unroll
    for (int off = 32; off > 0; off >>= 1) lsum += __shfl_down(lsum, off, 64);
    if ((tid & 63) == 0) red[tid >> 6] = lsum;
    __syncthreads();
    if (tid == 0) ws[1024 + blk] = red[0] + red[1] + red[2] + red[3];

    // one-hot 1.0 fixups (ordered after zero-stores by the barriers above)
    if (tid < 128) {
        const int ix = idx_sh[tid];
        float4 v = make_float4(0.f, 0.f, 0.f, 0.f);
        ((float*)&v)[ix & 3] = 1.0f;
        sub4[tid * 128 + (ix >> 2)] = v;
    }
}

__global__ void vq_final(float* __restrict__ out, const float* __restrict__ ws) {
    __shared__ float sl[512], sp[512];
    int t = threadIdx.x;                              // 512 threads, 1 block
    sl[t] = ws[1024 + t] + ws[1536 + t] + ws[2048 + t] + ws[2560 + t];
    int cnt = ((const int*)ws)[t];
    float p = (float)cnt * (1.0f / 262144.0f);
    sp[t] = p * logf(p + 1e-10f);
    __syncthreads();
    for (int off = 256; off > 0; off >>= 1) {
        if (t < off) { sl[t] += sl[t + off]; sp[t] += sp[t + off]; }
        __syncthreads();
    }
    if (t == 0) {
        float m = sl[0] * (1.0f / 16777216.0f);       // /2^24 exact
        out[0]    = __fadd_rn(m, __fmul_rn(0.25f, m));
        out[POFF] = expf(-sp[0]);
    }
}

extern "C" void kernel_launch(void* const* d_in, const int* in_sizes, int n_in,
                              void* d_out, int out_size, void* d_ws, size_t ws_size,
                              hipStream_t stream) {
    const float* in  = (const float*)d_in[0];
    const float* emb = (const float*)d_in[1];
    float* out = (float*)d_out;
    float* ws  = (float*)d_ws;   // needs 147456 B; harness scratch is larger

    hipMemsetAsync(d_ws, 0, 512 * sizeof(int), stream);            // histogram
    hipLaunchKernelGGL(vq_prep,  dim3(9),    dim3(256), 0, stream, emb, ws);
    hipLaunchKernelGGL(vq_main,  dim3(2048), dim3(256), 0, stream, in, emb, out, ws);
    hipLaunchKernelGGL(vq_final, dim3(1),    dim3(512), 0, stream, out, ws);
}